// Round 1
// baseline (675.486 us; speedup 1.0000x reference)
//
#include <hip/hip_runtime.h>
#include <hip/hip_bf16.h>
#include <stdint.h>

#define BATCH 2
#define NN 32768
#define DIM 512
#define HEADS 8
#define INNER 512
#define G 32
#define M_ROWS (BATCH * NN)   // 65536
#define MAXCHUNK 576

typedef __attribute__((ext_vector_type(8))) short bf16x8;
typedef __attribute__((ext_vector_type(4))) float floatx4;

__device__ __forceinline__ void gl_lds16(const void* g, void* l) {
    __builtin_amdgcn_global_load_lds(
        (const __attribute__((address_space(1))) uint32_t*)g,
        (__attribute__((address_space(3))) uint32_t*)l, 16, 0, 0);
}

__device__ __forceinline__ short f2bs(float f) {
    __hip_bfloat16 h = __float2bfloat16(f);
    return *reinterpret_cast<short*>(&h);
}

// ---------------------------------------------------------------------------
// graph info + chunk table (sorted batch -> binary search; serial chunk build)
// ---------------------------------------------------------------------------
__global__ void graph_info_kernel(const int* __restrict__ batch,
                                  int* __restrict__ starts,
                                  int* __restrict__ sizes,
                                  float* __restrict__ inv,
                                  int* __restrict__ crow0,
                                  int* __restrict__ crows,
                                  int* __restrict__ cbg,
                                  int* __restrict__ cnt) {
    __shared__ int bound[G + 1];
    int g = threadIdx.x;
    if (g <= G) {
        int lo = 0, hi = NN;
        while (lo < hi) { int mid = (lo + hi) >> 1; if (batch[mid] < g) lo = mid + 1; else hi = mid; }
        bound[g] = lo;
    }
    __syncthreads();
    if (g < G) {
        int s0 = bound[g], s1 = bound[g + 1];
        starts[g] = s0;
        int c = s1 - s0;
        sizes[g] = c;
        inv[g] = c ? 1.0f / (float)c : 0.0f;
    }
    if (g == 0) {
        int c = 0;
        for (int b = 0; b < BATCH; b++)
            for (int gg = 0; gg < G; gg++) {
                int s = bound[gg], sz = bound[gg + 1] - s;
                for (int i = 0; i < sz; i += 128) {
                    crow0[c] = b * NN + s + i;
                    crows[c] = min(128, sz - i);
                    cbg[c]   = b * G + gg;
                    c++;
                }
            }
        *cnt = c;
    }
}

// ---------------------------------------------------------------------------
// fp32 -> bf16 convert, 8 elements/thread
// ---------------------------------------------------------------------------
__global__ __launch_bounds__(256) void convert_kernel(
        const float* __restrict__ in, __hip_bfloat16* __restrict__ out, int n8) {
    int i = blockIdx.x * 256 + threadIdx.x;
    if (i >= n8) return;
    const float4* p = reinterpret_cast<const float4*>(in) + (size_t)i * 2;
    float4 a = p[0], b = p[1];
    __hip_bfloat16 o[8];
    o[0] = __float2bfloat16(a.x); o[1] = __float2bfloat16(a.y);
    o[2] = __float2bfloat16(a.z); o[3] = __float2bfloat16(a.w);
    o[4] = __float2bfloat16(b.x); o[5] = __float2bfloat16(b.y);
    o[6] = __float2bfloat16(b.z); o[7] = __float2bfloat16(b.w);
    *reinterpret_cast<float4*>(out + (size_t)i * 8) = *reinterpret_cast<float4*>(o);
}

// ---------------------------------------------------------------------------
// QKV GEMM, 128x128 tile, global_load_lds, bf16 MFMA, fused LN/q-scale.
// q written in [B][N][h*64+d] row-major (final-GEMM A layout).
// k,v now written TRANSPOSED: [b,h,d,n] (node-major rows) so the ktv kernel
// can load its MFMA fragments as contiguous 16B vectors straight from global.
// Stores stay 64 scalar 2B/thread (same count as before); each 64B line is
// fully covered within one 128-row tile, so L2 merges to full-line writes.
// ---------------------------------------------------------------------------
__global__ __launch_bounds__(256) void qkv_gemm_kernel(
        const __hip_bfloat16* __restrict__ xb, const __hip_bfloat16* __restrict__ wb,
        const float* __restrict__ ln1w, const float* __restrict__ ln1b,
        const float* __restrict__ ln2w, const float* __restrict__ ln2b,
        const float* __restrict__ inv, const int* __restrict__ batch,
        __hip_bfloat16* __restrict__ qn, __hip_bfloat16* __restrict__ kb,
        __hip_bfloat16* __restrict__ vb) {
    __shared__ __hip_bfloat16 As[128][32];
    __shared__ __hip_bfloat16 Bs[128][32];
    const int row0 = blockIdx.y * 128;
    const int col0 = blockIdx.x * 128;
    const int t = threadIdx.x;
    const int lane = t & 63;
    const int wave = t >> 6;
    const int wr = wave >> 1, wc = wave & 1;
    const int quad = lane >> 4, lr = lane & 15;

    floatx4 acc[4][4] = {};

    const int srow = t >> 2;
    const int scol = (t & 3) * 8;
    const __hip_bfloat16* gA = xb + (size_t)(row0 + srow) * DIM + scol;
    const __hip_bfloat16* gB = wb + (size_t)(col0 + srow) * DIM + scol;
    char* lA = (char*)&As[0][0] + t * 16;
    char* lB = (char*)&Bs[0][0] + t * 16;

    for (int k0 = 0; k0 < DIM; k0 += 32) {
        gl_lds16(gA + k0, lA);
        gl_lds16(gA + (size_t)64 * DIM + k0, lA + 4096);
        gl_lds16(gB + k0, lB);
        gl_lds16(gB + (size_t)64 * DIM + k0, lB + 4096);
        __syncthreads();
        bf16x8 af[4], bf[4];
        #pragma unroll
        for (int mt = 0; mt < 4; mt++)
            af[mt] = *reinterpret_cast<const bf16x8*>(&As[wr * 64 + mt * 16 + lr][quad * 8]);
        #pragma unroll
        for (int nt = 0; nt < 4; nt++)
            bf[nt] = *reinterpret_cast<const bf16x8*>(&Bs[wc * 64 + nt * 16 + lr][quad * 8]);
        #pragma unroll
        for (int mt = 0; mt < 4; mt++)
            #pragma unroll
            for (int nt = 0; nt < 4; nt++)
                acc[mt][nt] = __builtin_amdgcn_mfma_f32_16x16x32_bf16(af[mt], bf[nt], acc[mt][nt], 0, 0, 0);
        __syncthreads();
    }

    const int colw = col0 + wc * 64;
    const int sel = colw >> 9;               // 0=q 1=k 2=v
    const int hh = (colw & 511) >> 6;

    float lw[4], lb[4];
    if (sel) {
        const float* w = (sel == 1) ? ln1w : ln2w;
        const float* bb = (sel == 1) ? ln1b : ln2b;
        #pragma unroll
        for (int nt = 0; nt < 4; nt++) { lw[nt] = w[nt * 16 + lr]; lb[nt] = bb[nt * 16 + lr]; }
    }
    __hip_bfloat16* dstkv = (sel == 1) ? kb : vb;

    #pragma unroll
    for (int mt = 0; mt < 4; mt++) {
        #pragma unroll
        for (int reg = 0; reg < 4; reg++) {
            int row = row0 + wr * 64 + mt * 16 + quad * 4 + reg;
            int b_ = row >> 15;
            int n = row & (NN - 1);
            float v0 = acc[mt][0][reg], v1 = acc[mt][1][reg],
                  v2 = acc[mt][2][reg], v3 = acc[mt][3][reg];
            if (sel == 0) {
                float s = inv[batch[n]];
                v0 *= s; v1 *= s; v2 *= s; v3 *= s;
                size_t base = ((size_t)b_ * NN + n) * INNER + hh * 64;
                qn[base + 0 * 16 + lr] = __float2bfloat16(v0);
                qn[base + 1 * 16 + lr] = __float2bfloat16(v1);
                qn[base + 2 * 16 + lr] = __float2bfloat16(v2);
                qn[base + 3 * 16 + lr] = __float2bfloat16(v3);
            } else {
                float s = v0 + v1 + v2 + v3;
                s += __shfl_xor(s, 1); s += __shfl_xor(s, 2);
                s += __shfl_xor(s, 4); s += __shfl_xor(s, 8);
                float mu = s * (1.0f / 64.0f);
                float d0 = v0 - mu, d1 = v1 - mu, d2 = v2 - mu, d3 = v3 - mu;
                float s2 = d0 * d0 + d1 * d1 + d2 * d2 + d3 * d3;
                s2 += __shfl_xor(s2, 1); s2 += __shfl_xor(s2, 2);
                s2 += __shfl_xor(s2, 4); s2 += __shfl_xor(s2, 8);
                float rstd = rsqrtf(s2 * (1.0f / 64.0f) + 1e-6f);
                v0 = d0 * rstd * lw[0] + lb[0];
                v1 = d1 * rstd * lw[1] + lb[1];
                v2 = d2 * rstd * lw[2] + lb[2];
                v3 = d3 * rstd * lw[3] + lb[3];
                // transposed store: [bh][d][n], d = nt*16 + lr
                size_t base = ((size_t)(b_ * HEADS + hh) * 64 + lr) * NN + n;
                dstkv[base + (size_t)(0 * 16) * NN] = __float2bfloat16(v0);
                dstkv[base + (size_t)(1 * 16) * NN] = __float2bfloat16(v1);
                dstkv[base + (size_t)(2 * 16) * NN] = __float2bfloat16(v2);
                dstkv[base + (size_t)(3 * 16) * NN] = __float2bfloat16(v3);
            }
        }
    }
}

// ---------------------------------------------------------------------------
// Fused ktv + W2 (REWORKED): k,v arrive transposed [bh][d][n], so every MFMA
// fragment is one aligned 16B global load (node-major). Phase 1 now has NO
// LDS and NO barriers: each of the 4 waves owns an independent stride-128
// sequence of 32-node chunks (8 loads + 16 MFMA per chunk), then a single
// cross-wave fp32 reduction through bank-padded LDS produces ktv in bf16.
// Phase 3 (W2T = w_out slice x ktv) unchanged.
// ---------------------------------------------------------------------------
__global__ __launch_bounds__(256) void ktv_w2_kernel(
        const short* __restrict__ kt, const short* __restrict__ vt,
        const short* __restrict__ wob,
        const int* __restrict__ starts, const int* __restrict__ sizes,
        short* __restrict__ w2t) {
    __shared__ alignas(16) float red[4][64][68];   // stride 68 fl: b128 hits all 32 banks
    __shared__ alignas(16) short kt_sh[64][72];
    const int bhg = blockIdx.x;
    const int g = bhg & 31;
    const int bh = bhg >> 5;
    const int b = bh >> 3;
    const int h = bh & 7;
    const int s0 = starts[g];
    const int sz = sizes[g];
    const int t = threadIdx.x;
    const int lane = t & 63;
    const int w = t >> 6;
    const int quad = lane >> 4, lr = lane & 15;

    const int n0 = s0 & ~31;       // 32-aligned chunk grid start (16B-aligned loads)
    const int n1 = s0 + sz;
    const size_t base_bh = (size_t)bh * 64 * NN;

    const short* kp[4];
    const short* vp[4];
    #pragma unroll
    for (int mt = 0; mt < 4; mt++) {
        kp[mt] = kt + base_bh + (size_t)(mt * 16 + lr) * NN + quad * 8;
        vp[mt] = vt + base_bh + (size_t)(mt * 16 + lr) * NN + quad * 8;
    }

    floatx4 acc[4][4] = {};
    for (int c = n0 + w * 32; c < n1; c += 128) {
        bf16x8 af[4], bfr[4];
        if (c >= s0 && c + 32 <= n1) {
            // interior chunk: pure vector loads
            #pragma unroll
            for (int mt = 0; mt < 4; mt++) {
                af[mt]  = *reinterpret_cast<const bf16x8*>(kp[mt] + c);
                bfr[mt] = *reinterpret_cast<const bf16x8*>(vp[mt] + c);
            }
        } else {
            // graph-boundary chunk: scalar masked (<=2 per wave per block)
            #pragma unroll
            for (int mt = 0; mt < 4; mt++)
                #pragma unroll
                for (int j = 0; j < 8; j++) {
                    int n = c + quad * 8 + j;
                    bool ok = (n >= s0) && (n < n1);
                    af[mt][j]  = ok ? kp[mt][c + j] : (short)0;
                    bfr[mt][j] = ok ? vp[mt][c + j] : (short)0;
                }
        }
        #pragma unroll
        for (int mt = 0; mt < 4; mt++)
            #pragma unroll
            for (int et = 0; et < 4; et++)
                acc[mt][et] = __builtin_amdgcn_mfma_f32_16x16x32_bf16(af[mt], bfr[et], acc[mt][et], 0, 0, 0);
    }

    // cross-wave reduction: wave-private slabs, then wave w reduces mt-tile w
    #pragma unroll
    for (int mt = 0; mt < 4; mt++)
        #pragma unroll
        for (int et = 0; et < 4; et++)
            *reinterpret_cast<floatx4*>(&red[w][lane][(mt * 4 + et) * 4]) = acc[mt][et];
    __syncthreads();
    {
        const int mt = w;
        #pragma unroll
        for (int et = 0; et < 4; et++) {
            floatx4 s = *reinterpret_cast<const floatx4*>(&red[0][lane][(mt * 4 + et) * 4]);
            #pragma unroll
            for (int w2 = 1; w2 < 4; w2++)
                s += *reinterpret_cast<const floatx4*>(&red[w2][lane][(mt * 4 + et) * 4]);
            #pragma unroll
            for (int reg = 0; reg < 4; reg++)
                kt_sh[mt * 16 + quad * 4 + reg][et * 16 + lr] = f2bs(s[reg]);
        }
    }
    __syncthreads();

    // phase 3: W2T rows [w*128, w*128+128) of this bg, cols h*64..h*64+63
    const short* wsl = wob + h * 64;
    short* w2 = w2t + (size_t)(b * G + g) * 512 * 512 + h * 64;
    bf16x8 b0[4], b1[4];
    #pragma unroll
    for (int dt = 0; dt < 4; dt++) {
        b0[dt] = *reinterpret_cast<const bf16x8*>(&kt_sh[dt * 16 + lr][quad * 8]);
        b1[dt] = *reinterpret_cast<const bf16x8*>(&kt_sh[dt * 16 + lr][quad * 8 + 32]);
    }
    for (int ct = 0; ct < 8; ct++) {
        int c = w * 128 + ct * 16 + lr;
        bf16x8 a0 = *reinterpret_cast<const bf16x8*>(wsl + (size_t)c * INNER + quad * 8);
        bf16x8 a1 = *reinterpret_cast<const bf16x8*>(wsl + (size_t)c * INNER + 32 + quad * 8);
        #pragma unroll
        for (int dt = 0; dt < 4; dt++) {
            floatx4 d = {0.f, 0.f, 0.f, 0.f};
            d = __builtin_amdgcn_mfma_f32_16x16x32_bf16(a0, b0[dt], d, 0, 0, 0);
            d = __builtin_amdgcn_mfma_f32_16x16x32_bf16(a1, b1[dt], d, 0, 0, 0);
            #pragma unroll
            for (int reg = 0; reg < 4; reg++) {
                int crow = w * 128 + ct * 16 + quad * 4 + reg;
                w2[(size_t)crow * 512 + dt * 16 + lr] = f2bs(d[reg]);
            }
        }
    }
}

// ---------------------------------------------------------------------------
// Final segmented GEMM: out[row,:] = qn[row,:] @ W2T[bg]^T + b_out  (fp32 out)
// Grid (4 col-tiles FAST, 576 chunks). Full-tile gl_lds staging; masked stores.
// ---------------------------------------------------------------------------
__global__ __launch_bounds__(256) void final_gemm_kernel(
        const __hip_bfloat16* __restrict__ qn, const __hip_bfloat16* __restrict__ w2t,
        const float* __restrict__ bias,
        const int* __restrict__ crow0, const int* __restrict__ crows,
        const int* __restrict__ cbg, const int* __restrict__ cnt,
        float* __restrict__ out) {
    const int chunk = blockIdx.y;
    if (chunk >= *cnt) return;
    __shared__ __hip_bfloat16 As[128][32];
    __shared__ __hip_bfloat16 Bs[128][32];
    const int row0  = crow0[chunk];
    const int nrows = crows[chunk];
    const int bg    = cbg[chunk];
    const int col0 = blockIdx.x * 128;
    const int t = threadIdx.x;
    const int lane = t & 63;
    const int wave = t >> 6;
    const int wr = wave >> 1, wc = wave & 1;
    const int quad = lane >> 4, lr = lane & 15;

    floatx4 acc[4][4] = {};

    const int srow = t >> 2;
    const int scol = (t & 3) * 8;
    const __hip_bfloat16* gA = qn + (size_t)(row0 + srow) * INNER + scol;
    const __hip_bfloat16* gB = w2t + (size_t)bg * 512 * 512 + (size_t)(col0 + srow) * 512 + scol;
    char* lA = (char*)&As[0][0] + t * 16;
    char* lB = (char*)&Bs[0][0] + t * 16;

    for (int k0 = 0; k0 < INNER; k0 += 32) {
        gl_lds16(gA + k0, lA);
        gl_lds16(gA + (size_t)64 * INNER + k0, lA + 4096);
        gl_lds16(gB + k0, lB);
        gl_lds16(gB + (size_t)64 * 512 + k0, lB + 4096);
        __syncthreads();
        bf16x8 af[4], bf[4];
        #pragma unroll
        for (int mt = 0; mt < 4; mt++)
            af[mt] = *reinterpret_cast<const bf16x8*>(&As[wr * 64 + mt * 16 + lr][quad * 8]);
        #pragma unroll
        for (int nt = 0; nt < 4; nt++)
            bf[nt] = *reinterpret_cast<const bf16x8*>(&Bs[wc * 64 + nt * 16 + lr][quad * 8]);
        #pragma unroll
        for (int mt = 0; mt < 4; mt++)
            #pragma unroll
            for (int nt = 0; nt < 4; nt++)
                acc[mt][nt] = __builtin_amdgcn_mfma_f32_16x16x32_bf16(af[mt], bf[nt], acc[mt][nt], 0, 0, 0);
        __syncthreads();
    }

    #pragma unroll
    for (int nt = 0; nt < 4; nt++) {
        int col = col0 + wc * 64 + nt * 16 + lr;
        float bv = bias[col];
        #pragma unroll
        for (int mt = 0; mt < 4; mt++)
            #pragma unroll
            for (int reg = 0; reg < 4; reg++) {
                int rl = wr * 64 + mt * 16 + quad * 4 + reg;
                if (rl < nrows)
                    out[(size_t)(row0 + rl) * DIM + col] = acc[mt][nt][reg] + bv;
            }
    }
}

// ---------------------------------------------------------------------------
extern "C" void kernel_launch(void* const* d_in, const int* in_sizes, int n_in,
                              void* d_out, int out_size, void* d_ws, size_t ws_size,
                              hipStream_t stream) {
    const float* x     = (const float*)d_in[0];
    const float* w_qkv = (const float*)d_in[1];
    const float* ln1w  = (const float*)d_in[2];
    const float* ln1b  = (const float*)d_in[3];
    const float* ln2w  = (const float*)d_in[4];
    const float* ln2b  = (const float*)d_in[5];
    const float* w_out = (const float*)d_in[6];
    const float* b_out = (const float*)d_in[7];
    const int*   batch = (const int*)d_in[8];
    float* out = (float*)d_out;

    char* ws = (char*)d_ws;
    const size_t MB = 1u << 20;
    __hip_bfloat16* qn  = (__hip_bfloat16*)(ws);              // 64 MiB
    __hip_bfloat16* kb  = (__hip_bfloat16*)(ws + 64 * MB);    // 64 MiB (transposed [bh][d][n])
    __hip_bfloat16* vb  = (__hip_bfloat16*)(ws + 128 * MB);   // 64 MiB (transposed [bh][d][n])
    // region [192,256): xb during convert+qkv, then W2T (32 MiB) afterwards
    __hip_bfloat16* xb  = (__hip_bfloat16*)(ws + 192 * MB);
    __hip_bfloat16* w2t = (__hip_bfloat16*)(ws + 192 * MB);
    __hip_bfloat16* wb  = (__hip_bfloat16*)(ws + 256 * MB);   // 1.5 MiB
    __hip_bfloat16* wob = (__hip_bfloat16*)(ws + 258 * MB);   // 0.5 MiB
    char* meta = ws + 259 * MB;
    int*   starts = (int*)(meta);
    int*   sizes  = (int*)(meta + 128);
    float* inv    = (float*)(meta + 256);
    int*   crow0  = (int*)(meta + 512);
    int*   crows  = (int*)(meta + 512 + 4096);
    int*   cbg    = (int*)(meta + 512 + 8192);
    int*   cnt    = (int*)(meta + 512 + 12288);

    graph_info_kernel<<<1, 64, 0, stream>>>(batch, starts, sizes, inv,
                                            crow0, crows, cbg, cnt);
    convert_kernel<<<(M_ROWS * DIM / 8 + 255) / 256, 256, 0, stream>>>(x, xb, M_ROWS * DIM / 8);
    convert_kernel<<<(3 * INNER * DIM / 8 + 255) / 256, 256, 0, stream>>>(w_qkv, wb, 3 * INNER * DIM / 8);
    convert_kernel<<<(DIM * INNER / 8 + 255) / 256, 256, 0, stream>>>(w_out, wob, DIM * INNER / 8);
    qkv_gemm_kernel<<<dim3((3 * INNER) / 128, M_ROWS / 128), 256, 0, stream>>>(
        xb, wb, ln1w, ln1b, ln2w, ln2b, inv, batch, qn, kb, vb);
    ktv_w2_kernel<<<BATCH * HEADS * G, 256, 0, stream>>>(
        (const short*)kb, (const short*)vb, (const short*)wob, starts, sizes, (short*)w2t);
    final_gemm_kernel<<<dim3(4, MAXCHUNK), 256, 0, stream>>>(
        qn, w2t, b_out, crow0, crows, cbg, cnt, out);
}

// Round 2
// 608.208 us; speedup vs baseline: 1.1106x; 1.1106x over previous
//
#include <hip/hip_runtime.h>
#include <hip/hip_bf16.h>
#include <stdint.h>

#define BATCH 2
#define NN 32768
#define DIM 512
#define HEADS 8
#define INNER 512
#define G 32
#define M_ROWS (BATCH * NN)   // 65536
#define MAXCHUNK 576

typedef __attribute__((ext_vector_type(8))) short bf16x8;
typedef __attribute__((ext_vector_type(4))) float floatx4;

__device__ __forceinline__ void gl_lds16(const void* g, void* l) {
    __builtin_amdgcn_global_load_lds(
        (const __attribute__((address_space(1))) uint32_t*)g,
        (__attribute__((address_space(3))) uint32_t*)l, 16, 0, 0);
}

__device__ __forceinline__ short f2bs(float f) {
    __hip_bfloat16 h = __float2bfloat16(f);
    return *reinterpret_cast<short*>(&h);
}

// bijective XCD-chunked remap (nb % 8 == 0): XCD x gets nb/8 consecutive ids
__device__ __forceinline__ int xcd_swizzle(int bid, int nb) {
    return (bid & 7) * (nb >> 3) + (bid >> 3);
}

// swizzled 16B-granule fragment read from a [rows][32] bf16 tile staged by
// gl_lds with pre-swizzled source columns (rule #21: both-sides-or-neither).
// granule slot = quad ^ ((r>>1)&3) spreads reads across 8 bank-quads.
__device__ __forceinline__ bf16x8 frag_ld(const char* base, int r, int quad) {
    return *reinterpret_cast<const bf16x8*>(base + r * 64 + ((quad ^ ((r >> 1) & 3)) << 4));
}

// ---------------------------------------------------------------------------
// graph info + chunk table (sorted batch -> binary search; serial chunk build)
// ---------------------------------------------------------------------------
__global__ void graph_info_kernel(const int* __restrict__ batch,
                                  int* __restrict__ starts,
                                  int* __restrict__ sizes,
                                  float* __restrict__ inv,
                                  int* __restrict__ crow0,
                                  int* __restrict__ crows,
                                  int* __restrict__ cbg,
                                  int* __restrict__ cnt) {
    __shared__ int bound[G + 1];
    int g = threadIdx.x;
    if (g <= G) {
        int lo = 0, hi = NN;
        while (lo < hi) { int mid = (lo + hi) >> 1; if (batch[mid] < g) lo = mid + 1; else hi = mid; }
        bound[g] = lo;
    }
    __syncthreads();
    if (g < G) {
        int s0 = bound[g], s1 = bound[g + 1];
        starts[g] = s0;
        int c = s1 - s0;
        sizes[g] = c;
        inv[g] = c ? 1.0f / (float)c : 0.0f;
    }
    if (g == 0) {
        int c = 0;
        for (int b = 0; b < BATCH; b++)
            for (int gg = 0; gg < G; gg++) {
                int s = bound[gg], sz = bound[gg + 1] - s;
                for (int i = 0; i < sz; i += 128) {
                    crow0[c] = b * NN + s + i;
                    crows[c] = min(128, sz - i);
                    cbg[c]   = b * G + gg;
                    c++;
                }
            }
        *cnt = c;
    }
}

// ---------------------------------------------------------------------------
// fp32 -> bf16 convert, 8 elements/thread
// ---------------------------------------------------------------------------
__global__ __launch_bounds__(256) void convert_kernel(
        const float* __restrict__ in, __hip_bfloat16* __restrict__ out, int n8) {
    int i = blockIdx.x * 256 + threadIdx.x;
    if (i >= n8) return;
    const float4* p = reinterpret_cast<const float4*>(in) + (size_t)i * 2;
    float4 a = p[0], b = p[1];
    __hip_bfloat16 o[8];
    o[0] = __float2bfloat16(a.x); o[1] = __float2bfloat16(a.y);
    o[2] = __float2bfloat16(a.z); o[3] = __float2bfloat16(a.w);
    o[4] = __float2bfloat16(b.x); o[5] = __float2bfloat16(b.y);
    o[6] = __float2bfloat16(b.z); o[7] = __float2bfloat16(b.w);
    *reinterpret_cast<float4*>(out + (size_t)i * 8) = *reinterpret_cast<float4*>(o);
}

// ---------------------------------------------------------------------------
// QKV GEMM, 128x128 tile, global_load_lds, bf16 MFMA, fused LN/q-scale.
//  - XCD-chunked block swizzle: each XCD owns 64 consecutive row-panels, so
//    the 12 col-tiles of a panel hit the same L2 (A fetched ~once).
//  - As/Bs granule swizzle (pre-swizzled global source col + XOR on read)
//    kills the stride-64B ds_read_b128 bank conflicts.
//  - q written [B][N][h*64+d] (unchanged). k,v written transposed [bh][d][n]
//    via an LDS restage: packed ds_write_b64 -> coalesced 256B-row stores.
// ---------------------------------------------------------------------------
__global__ __launch_bounds__(256) void qkv_gemm_kernel(
        const __hip_bfloat16* __restrict__ xb, const __hip_bfloat16* __restrict__ wb,
        const float* __restrict__ ln1w, const float* __restrict__ ln1b,
        const float* __restrict__ ln2w, const float* __restrict__ ln2b,
        const float* __restrict__ inv, const int* __restrict__ batch,
        __hip_bfloat16* __restrict__ qn, __hip_bfloat16* __restrict__ kb,
        __hip_bfloat16* __restrict__ vb) {
    __shared__ alignas(16) char smem[32768];   // As 8K | Bs 8K ; reused as T 32K
    int bid = xcd_swizzle(blockIdx.y * 12 + blockIdx.x, 12 * 512);
    const int row0 = (bid / 12) * 128;
    const int col0 = (bid % 12) * 128;
    const int t = threadIdx.x;
    const int lane = t & 63;
    const int wave = t >> 6;
    const int wr = wave >> 1, wc = wave & 1;
    const int quad = lane >> 4, lr = lane & 15;

    floatx4 acc[4][4] = {};

    const int srow = t >> 2;
    const int scol = (((t & 3) ^ ((t >> 3) & 3))) * 8;   // pre-swizzled source col
    const __hip_bfloat16* gA = xb + (size_t)(row0 + srow) * DIM + scol;
    const __hip_bfloat16* gB = wb + (size_t)(col0 + srow) * DIM + scol;
    char* lA = smem + t * 16;
    char* lB = smem + 8192 + t * 16;

    for (int k0 = 0; k0 < DIM; k0 += 32) {
        gl_lds16(gA + k0, lA);
        gl_lds16(gA + (size_t)64 * DIM + k0, lA + 4096);
        gl_lds16(gB + k0, lB);
        gl_lds16(gB + (size_t)64 * DIM + k0, lB + 4096);
        __syncthreads();
        bf16x8 af[4], bf[4];
        #pragma unroll
        for (int mt = 0; mt < 4; mt++)
            af[mt] = frag_ld(smem, wr * 64 + mt * 16 + lr, quad);
        #pragma unroll
        for (int nt = 0; nt < 4; nt++)
            bf[nt] = frag_ld(smem + 8192, wc * 64 + nt * 16 + lr, quad);
        #pragma unroll
        for (int mt = 0; mt < 4; mt++)
            #pragma unroll
            for (int nt = 0; nt < 4; nt++)
                acc[mt][nt] = __builtin_amdgcn_mfma_f32_16x16x32_bf16(af[mt], bf[nt], acc[mt][nt], 0, 0, 0);
        __syncthreads();
    }

    // col0 is a multiple of 128 and q/k/v boundaries are at 512/1024: every
    // block is uniformly q, k, or v.
    const int sel = (col0 + wc * 64) >> 9;   // 0=q 1=k 2=v (uniform per block)
    const int hh = ((col0 + wc * 64) & 511) >> 6;

    if (sel == 0) {
        #pragma unroll
        for (int mt = 0; mt < 4; mt++) {
            #pragma unroll
            for (int reg = 0; reg < 4; reg++) {
                int row = row0 + wr * 64 + mt * 16 + quad * 4 + reg;
                int b_ = row >> 15;
                int n = row & (NN - 1);
                float s = inv[batch[n]];
                float v0 = acc[mt][0][reg] * s, v1 = acc[mt][1][reg] * s,
                      v2 = acc[mt][2][reg] * s, v3 = acc[mt][3][reg] * s;
                size_t base = ((size_t)b_ * NN + n) * INNER + hh * 64;
                qn[base + 0 * 16 + lr] = __float2bfloat16(v0);
                qn[base + 1 * 16 + lr] = __float2bfloat16(v1);
                qn[base + 2 * 16 + lr] = __float2bfloat16(v2);
                qn[base + 3 * 16 + lr] = __float2bfloat16(v3);
            }
        }
    } else {
        // ---- k/v: LN, then LDS restage T[d_local][n_local] (swizzled) ----
        const float* w  = (sel == 1) ? ln1w : ln2w;
        const float* bb = (sel == 1) ? ln1b : ln2b;
        float lw[4], lb[4];
        #pragma unroll
        for (int nt = 0; nt < 4; nt++) { lw[nt] = w[nt * 16 + lr]; lb[nt] = bb[nt * 16 + lr]; }
        __hip_bfloat16* dstkv = (sel == 1) ? kb : vb;
        short* T = (short*)smem;           // 128 x 128 bf16, n-granule XOR swizzle

        #pragma unroll
        for (int mt = 0; mt < 4; mt++) {
            float f[4][4];                 // [reg][nt]
            #pragma unroll
            for (int reg = 0; reg < 4; reg++) {
                float v0 = acc[mt][0][reg], v1 = acc[mt][1][reg],
                      v2 = acc[mt][2][reg], v3 = acc[mt][3][reg];
                float s = v0 + v1 + v2 + v3;
                s += __shfl_xor(s, 1); s += __shfl_xor(s, 2);
                s += __shfl_xor(s, 4); s += __shfl_xor(s, 8);
                float mu = s * (1.0f / 64.0f);
                float d0 = v0 - mu, d1 = v1 - mu, d2 = v2 - mu, d3 = v3 - mu;
                float s2 = d0 * d0 + d1 * d1 + d2 * d2 + d3 * d3;
                s2 += __shfl_xor(s2, 1); s2 += __shfl_xor(s2, 2);
                s2 += __shfl_xor(s2, 4); s2 += __shfl_xor(s2, 8);
                float rstd = rsqrtf(s2 * (1.0f / 64.0f) + 1e-6f);
                f[reg][0] = d0 * rstd * lw[0] + lb[0];
                f[reg][1] = d1 * rstd * lw[1] + lb[1];
                f[reg][2] = d2 * rstd * lw[2] + lb[2];
                f[reg][3] = d3 * rstd * lw[3] + lb[3];
            }
            const int c0 = wr * 64 + mt * 16 + quad * 4;   // n_local base (4 consecutive)
            #pragma unroll
            for (int nt = 0; nt < 4; nt++) {
                int r = wc * 64 + nt * 16 + lr;            // d_local
                int idx = r * 128 + (((c0 >> 3) ^ (r & 15)) << 3) + (c0 & 7);
                short4 pk;
                pk.x = f2bs(f[0][nt]); pk.y = f2bs(f[1][nt]);
                pk.z = f2bs(f[2][nt]); pk.w = f2bs(f[3][nt]);
                *reinterpret_cast<short4*>(&T[idx]) = pk;  // packed ds_write_b64
            }
        }
        __syncthreads();
        // coalesced stores: 16 lanes cover one full 256B row (128 n) per instr
        const int b_ = row0 >> 15;
        const int n0 = row0 & (NN - 1);
        const int gidx = lane & 15;
        const int rbase = wave * 32 + (lane >> 4) * 8;
        short* dsts = (short*)dstkv;
        #pragma unroll
        for (int i = 0; i < 8; i++) {
            int r = rbase + i;                             // d_local 0..127
            int idx = r * 128 + ((gidx ^ (r & 15)) << 3);
            bf16x8 val = *reinterpret_cast<const bf16x8*>(&T[idx]);
            int j = (col0 & 511) + r;                      // 0..511 within k or v
            size_t addr = ((size_t)((b_ * HEADS + (j >> 6)) * 64 + (j & 63))) * NN
                          + n0 + gidx * 8;
            *reinterpret_cast<bf16x8*>(&dsts[addr]) = val;
        }
    }
}

// ---------------------------------------------------------------------------
// Fused ktv + W2: k,v arrive transposed [bh][d][n]; phase 1 has no LDS and no
// barriers (each wave owns stride-128 chunk sequence, 8 vec loads + 16 MFMA
// per 32-node chunk), then one cross-wave fp32 reduction. Phase 3 unchanged.
// ---------------------------------------------------------------------------
__global__ __launch_bounds__(256) void ktv_w2_kernel(
        const short* __restrict__ kt, const short* __restrict__ vt,
        const short* __restrict__ wob,
        const int* __restrict__ starts, const int* __restrict__ sizes,
        short* __restrict__ w2t) {
    __shared__ alignas(16) float red[4][64][68];
    __shared__ alignas(16) short kt_sh[64][72];
    const int bhg = blockIdx.x;
    const int g = bhg & 31;
    const int bh = bhg >> 5;
    const int b = bh >> 3;
    const int h = bh & 7;
    const int s0 = starts[g];
    const int sz = sizes[g];
    const int t = threadIdx.x;
    const int lane = t & 63;
    const int w = t >> 6;
    const int quad = lane >> 4, lr = lane & 15;

    const int n0 = s0 & ~31;
    const int n1 = s0 + sz;
    const size_t base_bh = (size_t)bh * 64 * NN;

    const short* kp[4];
    const short* vp[4];
    #pragma unroll
    for (int mt = 0; mt < 4; mt++) {
        kp[mt] = kt + base_bh + (size_t)(mt * 16 + lr) * NN + quad * 8;
        vp[mt] = vt + base_bh + (size_t)(mt * 16 + lr) * NN + quad * 8;
    }

    floatx4 acc[4][4] = {};
    for (int c = n0 + w * 32; c < n1; c += 128) {
        bf16x8 af[4], bfr[4];
        if (c >= s0 && c + 32 <= n1) {
            #pragma unroll
            for (int mt = 0; mt < 4; mt++) {
                af[mt]  = *reinterpret_cast<const bf16x8*>(kp[mt] + c);
                bfr[mt] = *reinterpret_cast<const bf16x8*>(vp[mt] + c);
            }
        } else {
            #pragma unroll
            for (int mt = 0; mt < 4; mt++)
                #pragma unroll
                for (int j = 0; j < 8; j++) {
                    int n = c + quad * 8 + j;
                    bool ok = (n >= s0) && (n < n1);
                    af[mt][j]  = ok ? kp[mt][c + j] : (short)0;
                    bfr[mt][j] = ok ? vp[mt][c + j] : (short)0;
                }
        }
        #pragma unroll
        for (int mt = 0; mt < 4; mt++)
            #pragma unroll
            for (int et = 0; et < 4; et++)
                acc[mt][et] = __builtin_amdgcn_mfma_f32_16x16x32_bf16(af[mt], bfr[et], acc[mt][et], 0, 0, 0);
    }

    #pragma unroll
    for (int mt = 0; mt < 4; mt++)
        #pragma unroll
        for (int et = 0; et < 4; et++)
            *reinterpret_cast<floatx4*>(&red[w][lane][(mt * 4 + et) * 4]) = acc[mt][et];
    __syncthreads();
    {
        const int mt = w;
        #pragma unroll
        for (int et = 0; et < 4; et++) {
            floatx4 s = *reinterpret_cast<const floatx4*>(&red[0][lane][(mt * 4 + et) * 4]);
            #pragma unroll
            for (int w2 = 1; w2 < 4; w2++)
                s += *reinterpret_cast<const floatx4*>(&red[w2][lane][(mt * 4 + et) * 4]);
            #pragma unroll
            for (int reg = 0; reg < 4; reg++)
                kt_sh[mt * 16 + quad * 4 + reg][et * 16 + lr] = f2bs(s[reg]);
        }
    }
    __syncthreads();

    const short* wsl = wob + h * 64;
    short* w2 = w2t + (size_t)(b * G + g) * 512 * 512 + h * 64;
    bf16x8 b0[4], b1[4];
    #pragma unroll
    for (int dt = 0; dt < 4; dt++) {
        b0[dt] = *reinterpret_cast<const bf16x8*>(&kt_sh[dt * 16 + lr][quad * 8]);
        b1[dt] = *reinterpret_cast<const bf16x8*>(&kt_sh[dt * 16 + lr][quad * 8 + 32]);
    }
    for (int ct = 0; ct < 8; ct++) {
        int c = w * 128 + ct * 16 + lr;
        bf16x8 a0 = *reinterpret_cast<const bf16x8*>(wsl + (size_t)c * INNER + quad * 8);
        bf16x8 a1 = *reinterpret_cast<const bf16x8*>(wsl + (size_t)c * INNER + 32 + quad * 8);
        #pragma unroll
        for (int dt = 0; dt < 4; dt++) {
            floatx4 d = {0.f, 0.f, 0.f, 0.f};
            d = __builtin_amdgcn_mfma_f32_16x16x32_bf16(a0, b0[dt], d, 0, 0, 0);
            d = __builtin_amdgcn_mfma_f32_16x16x32_bf16(a1, b1[dt], d, 0, 0, 0);
            #pragma unroll
            for (int reg = 0; reg < 4; reg++) {
                int crow = w * 128 + ct * 16 + quad * 4 + reg;
                w2[(size_t)crow * 512 + dt * 16 + lr] = f2bs(d[reg]);
            }
        }
    }
}

// ---------------------------------------------------------------------------
// Final segmented GEMM: out[row,:] = qn[row,:] @ W2T[bg]^T + b_out  (fp32 out)
// XCD-chunked swizzle (A-chunk + same-bg B panels stay in one L2); swizzled
// As/Bs fragment reads as in qkv.
// ---------------------------------------------------------------------------
__global__ __launch_bounds__(256) void final_gemm_kernel(
        const __hip_bfloat16* __restrict__ qn, const __hip_bfloat16* __restrict__ w2t,
        const float* __restrict__ bias,
        const int* __restrict__ crow0, const int* __restrict__ crows,
        const int* __restrict__ cbg, const int* __restrict__ cnt,
        float* __restrict__ out) {
    __shared__ alignas(16) char smem[16384];
    int bid = xcd_swizzle(blockIdx.y * 4 + blockIdx.x, 4 * MAXCHUNK);
    const int chunk = bid >> 2;
    if (chunk >= *cnt) return;
    const int row0  = crow0[chunk];
    const int nrows = crows[chunk];
    const int bg    = cbg[chunk];
    const int col0 = (bid & 3) * 128;
    const int t = threadIdx.x;
    const int lane = t & 63;
    const int wave = t >> 6;
    const int wr = wave >> 1, wc = wave & 1;
    const int quad = lane >> 4, lr = lane & 15;

    floatx4 acc[4][4] = {};

    const int srow = t >> 2;
    const int scol = (((t & 3) ^ ((t >> 3) & 3))) * 8;
    const __hip_bfloat16* gA = qn + (size_t)(row0 + srow) * INNER + scol;
    const __hip_bfloat16* gB = w2t + (size_t)bg * 512 * 512 + (size_t)(col0 + srow) * 512 + scol;
    char* lA = smem + t * 16;
    char* lB = smem + 8192 + t * 16;

    for (int k0 = 0; k0 < INNER; k0 += 32) {
        gl_lds16(gA + k0, lA);
        gl_lds16(gA + (size_t)64 * INNER + k0, lA + 4096);
        gl_lds16(gB + k0, lB);
        gl_lds16(gB + (size_t)64 * 512 + k0, lB + 4096);
        __syncthreads();
        bf16x8 af[4], bf[4];
        #pragma unroll
        for (int mt = 0; mt < 4; mt++)
            af[mt] = frag_ld(smem, wr * 64 + mt * 16 + lr, quad);
        #pragma unroll
        for (int nt = 0; nt < 4; nt++)
            bf[nt] = frag_ld(smem + 8192, wc * 64 + nt * 16 + lr, quad);
        #pragma unroll
        for (int mt = 0; mt < 4; mt++)
            #pragma unroll
            for (int nt = 0; nt < 4; nt++)
                acc[mt][nt] = __builtin_amdgcn_mfma_f32_16x16x32_bf16(af[mt], bf[nt], acc[mt][nt], 0, 0, 0);
        __syncthreads();
    }

    #pragma unroll
    for (int nt = 0; nt < 4; nt++) {
        int col = col0 + wc * 64 + nt * 16 + lr;
        float bv = bias[col];
        #pragma unroll
        for (int mt = 0; mt < 4; mt++)
            #pragma unroll
            for (int reg = 0; reg < 4; reg++) {
                int rl = wr * 64 + mt * 16 + quad * 4 + reg;
                if (rl < nrows)
                    out[(size_t)(row0 + rl) * DIM + col] = acc[mt][nt][reg] + bv;
            }
    }
}

// ---------------------------------------------------------------------------
extern "C" void kernel_launch(void* const* d_in, const int* in_sizes, int n_in,
                              void* d_out, int out_size, void* d_ws, size_t ws_size,
                              hipStream_t stream) {
    const float* x     = (const float*)d_in[0];
    const float* w_qkv = (const float*)d_in[1];
    const float* ln1w  = (const float*)d_in[2];
    const float* ln1b  = (const float*)d_in[3];
    const float* ln2w  = (const float*)d_in[4];
    const float* ln2b  = (const float*)d_in[5];
    const float* w_out = (const float*)d_in[6];
    const float* b_out = (const float*)d_in[7];
    const int*   batch = (const int*)d_in[8];
    float* out = (float*)d_out;

    char* ws = (char*)d_ws;
    const size_t MB = 1u << 20;
    __hip_bfloat16* qn  = (__hip_bfloat16*)(ws);              // 64 MiB
    __hip_bfloat16* kb  = (__hip_bfloat16*)(ws + 64 * MB);    // 64 MiB (transposed [bh][d][n])
    __hip_bfloat16* vb  = (__hip_bfloat16*)(ws + 128 * MB);   // 64 MiB (transposed [bh][d][n])
    __hip_bfloat16* xb  = (__hip_bfloat16*)(ws + 192 * MB);   // xb then w2t
    __hip_bfloat16* w2t = (__hip_bfloat16*)(ws + 192 * MB);
    __hip_bfloat16* wb  = (__hip_bfloat16*)(ws + 256 * MB);   // 1.5 MiB
    __hip_bfloat16* wob = (__hip_bfloat16*)(ws + 258 * MB);   // 0.5 MiB
    char* meta = ws + 259 * MB;
    int*   starts = (int*)(meta);
    int*   sizes  = (int*)(meta + 128);
    float* inv    = (float*)(meta + 256);
    int*   crow0  = (int*)(meta + 512);
    int*   crows  = (int*)(meta + 512 + 4096);
    int*   cbg    = (int*)(meta + 512 + 8192);
    int*   cnt    = (int*)(meta + 512 + 12288);

    graph_info_kernel<<<1, 64, 0, stream>>>(batch, starts, sizes, inv,
                                            crow0, crows, cbg, cnt);
    convert_kernel<<<(M_ROWS * DIM / 8 + 255) / 256, 256, 0, stream>>>(x, xb, M_ROWS * DIM / 8);
    convert_kernel<<<(3 * INNER * DIM / 8 + 255) / 256, 256, 0, stream>>>(w_qkv, wb, 3 * INNER * DIM / 8);
    convert_kernel<<<(DIM * INNER / 8 + 255) / 256, 256, 0, stream>>>(w_out, wob, DIM * INNER / 8);
    qkv_gemm_kernel<<<dim3((3 * INNER) / 128, M_ROWS / 128), 256, 0, stream>>>(
        xb, wb, ln1w, ln1b, ln2w, ln2b, inv, batch, qn, kb, vb);
    ktv_w2_kernel<<<BATCH * HEADS * G, 256, 0, stream>>>(
        (const short*)kb, (const short*)vb, (const short*)wob, starts, sizes, (short*)w2t);
    final_gemm_kernel<<<dim3(4, MAXCHUNK), 256, 0, stream>>>(
        qn, w2t, b_out, crow0, crows, cbg, cnt, out);
}

// Round 3
// 556.644 us; speedup vs baseline: 1.2135x; 1.0926x over previous
//
#include <hip/hip_runtime.h>
#include <hip/hip_bf16.h>
#include <stdint.h>

#define BATCH 2
#define NN 32768
#define DIM 512
#define HEADS 8
#define INNER 512
#define G 32
#define M_ROWS (BATCH * NN)   // 65536
#define MAXCHUNK 576

typedef __attribute__((ext_vector_type(8))) short bf16x8;
typedef __attribute__((ext_vector_type(4))) float floatx4;

__device__ __forceinline__ void gl_lds16(const void* g, void* l) {
    __builtin_amdgcn_global_load_lds(
        (const __attribute__((address_space(1))) uint32_t*)g,
        (__attribute__((address_space(3))) uint32_t*)l, 16, 0, 0);
}

__device__ __forceinline__ short f2bs(float f) {
    __hip_bfloat16 h = __float2bfloat16(f);
    return *reinterpret_cast<short*>(&h);
}

// bijective XCD-chunked remap (nb % 8 == 0): XCD x gets nb/8 consecutive ids
__device__ __forceinline__ int xcd_swizzle(int bid, int nb) {
    return (bid & 7) * (nb >> 3) + (bid >> 3);
}

// swizzled 16B-granule fragment read from a [rows][32] bf16 tile staged by
// gl_lds with pre-swizzled source columns (rule #21: both-sides-or-neither).
__device__ __forceinline__ bf16x8 frag_ld(const char* base, int r, int quad) {
    return *reinterpret_cast<const bf16x8*>(base + r * 64 + ((quad ^ ((r >> 1) & 3)) << 4));
}

// ---------------------------------------------------------------------------
// graph info + chunk table (sorted batch -> binary search; serial chunk build)
// ---------------------------------------------------------------------------
__global__ void graph_info_kernel(const int* __restrict__ batch,
                                  int* __restrict__ starts,
                                  int* __restrict__ sizes,
                                  float* __restrict__ inv,
                                  int* __restrict__ crow0,
                                  int* __restrict__ crows,
                                  int* __restrict__ cbg,
                                  int* __restrict__ cnt) {
    __shared__ int bound[G + 1];
    int g = threadIdx.x;
    if (g <= G) {
        int lo = 0, hi = NN;
        while (lo < hi) { int mid = (lo + hi) >> 1; if (batch[mid] < g) lo = mid + 1; else hi = mid; }
        bound[g] = lo;
    }
    __syncthreads();
    if (g < G) {
        int s0 = bound[g], s1 = bound[g + 1];
        starts[g] = s0;
        int c = s1 - s0;
        sizes[g] = c;
        inv[g] = c ? 1.0f / (float)c : 0.0f;
    }
    if (g == 0) {
        int c = 0;
        for (int b = 0; b < BATCH; b++)
            for (int gg = 0; gg < G; gg++) {
                int s = bound[gg], sz = bound[gg + 1] - s;
                for (int i = 0; i < sz; i += 128) {
                    crow0[c] = b * NN + s + i;
                    crows[c] = min(128, sz - i);
                    cbg[c]   = b * G + gg;
                    c++;
                }
            }
        *cnt = c;
    }
}

// ---------------------------------------------------------------------------
// fp32 -> bf16 convert: one launch covers x (blocks [0,16384)), w_qkv
// ([16384,16768)), w_out ([16768,16896)). All ranges are exact multiples.
// ---------------------------------------------------------------------------
__global__ __launch_bounds__(256) void convert3_kernel(
        const float* __restrict__ x, const float* __restrict__ wqkv,
        const float* __restrict__ wout,
        __hip_bfloat16* __restrict__ xb, __hip_bfloat16* __restrict__ wb,
        __hip_bfloat16* __restrict__ wob) {
    int blk = blockIdx.x;
    const float* in;
    __hip_bfloat16* out;
    int i;
    if (blk < 16384)      { in = x;    out = xb;  i = blk * 256 + threadIdx.x; }
    else if (blk < 16768) { in = wqkv; out = wb;  i = (blk - 16384) * 256 + threadIdx.x; }
    else                  { in = wout; out = wob; i = (blk - 16768) * 256 + threadIdx.x; }
    const float4* p = reinterpret_cast<const float4*>(in) + (size_t)i * 2;
    float4 a = p[0], b = p[1];
    __hip_bfloat16 o[8];
    o[0] = __float2bfloat16(a.x); o[1] = __float2bfloat16(a.y);
    o[2] = __float2bfloat16(a.z); o[3] = __float2bfloat16(a.w);
    o[4] = __float2bfloat16(b.x); o[5] = __float2bfloat16(b.y);
    o[6] = __float2bfloat16(b.z); o[7] = __float2bfloat16(b.w);
    *reinterpret_cast<float4*>(out + (size_t)i * 8) = *reinterpret_cast<float4*>(o);
}

// ---------------------------------------------------------------------------
// QKV GEMM, 128x128 tile, 2-phase double-buffered gl_lds staging:
//   prologue stage -> { stage(next buf) ; ds_read+MFMA(cur buf) ; barrier }
// One barrier per K-step; staged loads fly during the compute phase.
// __launch_bounds__(256,3): cap regs at 512/3 so 3 blocks/CU fit
// (116 VGPR + 64 AGPR = 180 > 170 was limiting us to 2 blocks/CU).
// ---------------------------------------------------------------------------
__global__ __launch_bounds__(256, 3) void qkv_gemm_kernel(
        const __hip_bfloat16* __restrict__ xb, const __hip_bfloat16* __restrict__ wb,
        const float* __restrict__ ln1w, const float* __restrict__ ln1b,
        const float* __restrict__ ln2w, const float* __restrict__ ln2b,
        const float* __restrict__ inv, const int* __restrict__ batch,
        __hip_bfloat16* __restrict__ qn, __hip_bfloat16* __restrict__ kb,
        __hip_bfloat16* __restrict__ vb) {
    // A0 @0 | B0 @8K | A1 @16K | B1 @24K ; reused as T (32K) in epilogue
    __shared__ alignas(16) char smem[32768];
    int bid = xcd_swizzle(blockIdx.y * 12 + blockIdx.x, 12 * 512);
    const int row0 = (bid / 12) * 128;
    const int col0 = (bid % 12) * 128;
    const int t = threadIdx.x;
    const int lane = t & 63;
    const int wave = t >> 6;
    const int wr = wave >> 1, wc = wave & 1;
    const int quad = lane >> 4, lr = lane & 15;

    floatx4 acc[4][4] = {};

    const int srow = t >> 2;
    const int scol = (((t & 3) ^ ((t >> 3) & 3))) * 8;   // pre-swizzled source col
    const __hip_bfloat16* gA = xb + (size_t)(row0 + srow) * DIM + scol;
    const __hip_bfloat16* gB = wb + (size_t)(col0 + srow) * DIM + scol;
    char* lA = smem + t * 16;
    char* lB = smem + 8192 + t * 16;

    // prologue: stage K-step 0 into buffer 0
    gl_lds16(gA, lA);
    gl_lds16(gA + (size_t)64 * DIM, lA + 4096);
    gl_lds16(gB, lB);
    gl_lds16(gB + (size_t)64 * DIM, lB + 4096);
    __syncthreads();

    for (int it = 0; it < DIM / 32; ++it) {
        const int cb = (it & 1) << 14;
        const int nb = cb ^ 16384;
        const int k1 = (it + 1) * 32;
        if (k1 < DIM) {
            gl_lds16(gA + k1, lA + nb);
            gl_lds16(gA + (size_t)64 * DIM + k1, lA + nb + 4096);
            gl_lds16(gB + k1, lB + nb);
            gl_lds16(gB + (size_t)64 * DIM + k1, lB + nb + 4096);
        }
        bf16x8 af[4], bf[4];
        #pragma unroll
        for (int mt = 0; mt < 4; mt++)
            af[mt] = frag_ld(smem + cb, wr * 64 + mt * 16 + lr, quad);
        #pragma unroll
        for (int nt = 0; nt < 4; nt++)
            bf[nt] = frag_ld(smem + cb + 8192, wc * 64 + nt * 16 + lr, quad);
        #pragma unroll
        for (int mt = 0; mt < 4; mt++)
            #pragma unroll
            for (int nt = 0; nt < 4; nt++)
                acc[mt][nt] = __builtin_amdgcn_mfma_f32_16x16x32_bf16(af[mt], bf[nt], acc[mt][nt], 0, 0, 0);
        __syncthreads();
    }

    const int sel = (col0 + wc * 64) >> 9;   // 0=q 1=k 2=v (uniform per block)
    const int hh = ((col0 + wc * 64) & 511) >> 6;

    if (sel == 0) {
        #pragma unroll
        for (int mt = 0; mt < 4; mt++) {
            #pragma unroll
            for (int reg = 0; reg < 4; reg++) {
                int row = row0 + wr * 64 + mt * 16 + quad * 4 + reg;
                int b_ = row >> 15;
                int n = row & (NN - 1);
                float s = inv[batch[n]];
                float v0 = acc[mt][0][reg] * s, v1 = acc[mt][1][reg] * s,
                      v2 = acc[mt][2][reg] * s, v3 = acc[mt][3][reg] * s;
                size_t base = ((size_t)b_ * NN + n) * INNER + hh * 64;
                qn[base + 0 * 16 + lr] = __float2bfloat16(v0);
                qn[base + 1 * 16 + lr] = __float2bfloat16(v1);
                qn[base + 2 * 16 + lr] = __float2bfloat16(v2);
                qn[base + 3 * 16 + lr] = __float2bfloat16(v3);
            }
        }
    } else {
        // ---- k/v: LN, then LDS restage T[d_local][n_local] (swizzled) ----
        const float* w  = (sel == 1) ? ln1w : ln2w;
        const float* bb = (sel == 1) ? ln1b : ln2b;
        float lw[4], lb[4];
        #pragma unroll
        for (int nt = 0; nt < 4; nt++) { lw[nt] = w[nt * 16 + lr]; lb[nt] = bb[nt * 16 + lr]; }
        __hip_bfloat16* dstkv = (sel == 1) ? kb : vb;
        short* T = (short*)smem;           // 128 x 128 bf16, n-granule XOR swizzle

        #pragma unroll
        for (int mt = 0; mt < 4; mt++) {
            float f[4][4];                 // [reg][nt]
            #pragma unroll
            for (int reg = 0; reg < 4; reg++) {
                float v0 = acc[mt][0][reg], v1 = acc[mt][1][reg],
                      v2 = acc[mt][2][reg], v3 = acc[mt][3][reg];
                float s = v0 + v1 + v2 + v3;
                s += __shfl_xor(s, 1); s += __shfl_xor(s, 2);
                s += __shfl_xor(s, 4); s += __shfl_xor(s, 8);
                float mu = s * (1.0f / 64.0f);
                float d0 = v0 - mu, d1 = v1 - mu, d2 = v2 - mu, d3 = v3 - mu;
                float s2 = d0 * d0 + d1 * d1 + d2 * d2 + d3 * d3;
                s2 += __shfl_xor(s2, 1); s2 += __shfl_xor(s2, 2);
                s2 += __shfl_xor(s2, 4); s2 += __shfl_xor(s2, 8);
                float rstd = rsqrtf(s2 * (1.0f / 64.0f) + 1e-6f);
                f[reg][0] = d0 * rstd * lw[0] + lb[0];
                f[reg][1] = d1 * rstd * lw[1] + lb[1];
                f[reg][2] = d2 * rstd * lw[2] + lb[2];
                f[reg][3] = d3 * rstd * lw[3] + lb[3];
            }
            const int c0 = wr * 64 + mt * 16 + quad * 4;   // n_local base
            #pragma unroll
            for (int nt = 0; nt < 4; nt++) {
                int r = wc * 64 + nt * 16 + lr;            // d_local
                int idx = r * 128 + (((c0 >> 3) ^ (r & 15)) << 3) + (c0 & 7);
                short4 pk;
                pk.x = f2bs(f[0][nt]); pk.y = f2bs(f[1][nt]);
                pk.z = f2bs(f[2][nt]); pk.w = f2bs(f[3][nt]);
                *reinterpret_cast<short4*>(&T[idx]) = pk;  // packed ds_write_b64
            }
        }
        __syncthreads();
        const int b_ = row0 >> 15;
        const int n0 = row0 & (NN - 1);
        const int gidx = lane & 15;
        const int rbase = wave * 32 + (lane >> 4) * 8;
        short* dsts = (short*)dstkv;
        #pragma unroll
        for (int i = 0; i < 8; i++) {
            int r = rbase + i;                             // d_local 0..127
            int idx = r * 128 + ((gidx ^ (r & 15)) << 3);
            bf16x8 val = *reinterpret_cast<const bf16x8*>(&T[idx]);
            int j = (col0 & 511) + r;                      // 0..511 within k or v
            size_t addr = ((size_t)((b_ * HEADS + (j >> 6)) * 64 + (j & 63))) * NN
                          + n0 + gidx * 8;
            *reinterpret_cast<bf16x8*>(&dsts[addr]) = val;
        }
    }
}

// ---------------------------------------------------------------------------
// Fused ktv + W2: k,v arrive transposed [bh][d][n]; phase 1 has no LDS and no
// barriers (each wave owns stride-128 chunk sequence, 8 vec loads + 16 MFMA
// per 32-node chunk), then one cross-wave fp32 reduction. Phase 3 unchanged.
// ---------------------------------------------------------------------------
__global__ __launch_bounds__(256) void ktv_w2_kernel(
        const short* __restrict__ kt, const short* __restrict__ vt,
        const short* __restrict__ wob,
        const int* __restrict__ starts, const int* __restrict__ sizes,
        short* __restrict__ w2t) {
    __shared__ alignas(16) float red[4][64][68];
    __shared__ alignas(16) short kt_sh[64][72];
    const int bhg = blockIdx.x;
    const int g = bhg & 31;
    const int bh = bhg >> 5;
    const int b = bh >> 3;
    const int h = bh & 7;
    const int s0 = starts[g];
    const int sz = sizes[g];
    const int t = threadIdx.x;
    const int lane = t & 63;
    const int w = t >> 6;
    const int quad = lane >> 4, lr = lane & 15;

    const int n0 = s0 & ~31;
    const int n1 = s0 + sz;
    const size_t base_bh = (size_t)bh * 64 * NN;

    const short* kp[4];
    const short* vp[4];
    #pragma unroll
    for (int mt = 0; mt < 4; mt++) {
        kp[mt] = kt + base_bh + (size_t)(mt * 16 + lr) * NN + quad * 8;
        vp[mt] = vt + base_bh + (size_t)(mt * 16 + lr) * NN + quad * 8;
    }

    floatx4 acc[4][4] = {};
    for (int c = n0 + w * 32; c < n1; c += 128) {
        bf16x8 af[4], bfr[4];
        if (c >= s0 && c + 32 <= n1) {
            #pragma unroll
            for (int mt = 0; mt < 4; mt++) {
                af[mt]  = *reinterpret_cast<const bf16x8*>(kp[mt] + c);
                bfr[mt] = *reinterpret_cast<const bf16x8*>(vp[mt] + c);
            }
        } else {
            #pragma unroll
            for (int mt = 0; mt < 4; mt++)
                #pragma unroll
                for (int j = 0; j < 8; j++) {
                    int n = c + quad * 8 + j;
                    bool ok = (n >= s0) && (n < n1);
                    af[mt][j]  = ok ? kp[mt][c + j] : (short)0;
                    bfr[mt][j] = ok ? vp[mt][c + j] : (short)0;
                }
        }
        #pragma unroll
        for (int mt = 0; mt < 4; mt++)
            #pragma unroll
            for (int et = 0; et < 4; et++)
                acc[mt][et] = __builtin_amdgcn_mfma_f32_16x16x32_bf16(af[mt], bfr[et], acc[mt][et], 0, 0, 0);
    }

    #pragma unroll
    for (int mt = 0; mt < 4; mt++)
        #pragma unroll
        for (int et = 0; et < 4; et++)
            *reinterpret_cast<floatx4*>(&red[w][lane][(mt * 4 + et) * 4]) = acc[mt][et];
    __syncthreads();
    {
        const int mt = w;
        #pragma unroll
        for (int et = 0; et < 4; et++) {
            floatx4 s = *reinterpret_cast<const floatx4*>(&red[0][lane][(mt * 4 + et) * 4]);
            #pragma unroll
            for (int w2 = 1; w2 < 4; w2++)
                s += *reinterpret_cast<const floatx4*>(&red[w2][lane][(mt * 4 + et) * 4]);
            #pragma unroll
            for (int reg = 0; reg < 4; reg++)
                kt_sh[mt * 16 + quad * 4 + reg][et * 16 + lr] = f2bs(s[reg]);
        }
    }
    __syncthreads();

    const short* wsl = wob + h * 64;
    short* w2 = w2t + (size_t)(b * G + g) * 512 * 512 + h * 64;
    bf16x8 b0[4], b1[4];
    #pragma unroll
    for (int dt = 0; dt < 4; dt++) {
        b0[dt] = *reinterpret_cast<const bf16x8*>(&kt_sh[dt * 16 + lr][quad * 8]);
        b1[dt] = *reinterpret_cast<const bf16x8*>(&kt_sh[dt * 16 + lr][quad * 8 + 32]);
    }
    for (int ct = 0; ct < 8; ct++) {
        int c = w * 128 + ct * 16 + lr;
        bf16x8 a0 = *reinterpret_cast<const bf16x8*>(wsl + (size_t)c * INNER + quad * 8);
        bf16x8 a1 = *reinterpret_cast<const bf16x8*>(wsl + (size_t)c * INNER + 32 + quad * 8);
        #pragma unroll
        for (int dt = 0; dt < 4; dt++) {
            floatx4 d = {0.f, 0.f, 0.f, 0.f};
            d = __builtin_amdgcn_mfma_f32_16x16x32_bf16(a0, b0[dt], d, 0, 0, 0);
            d = __builtin_amdgcn_mfma_f32_16x16x32_bf16(a1, b1[dt], d, 0, 0, 0);
            #pragma unroll
            for (int reg = 0; reg < 4; reg++) {
                int crow = w * 128 + ct * 16 + quad * 4 + reg;
                w2[(size_t)crow * 512 + dt * 16 + lr] = f2bs(d[reg]);
            }
        }
    }
}

// ---------------------------------------------------------------------------
// Final segmented GEMM: out[row,:] = qn[row,:] @ W2T[bg]^T + b_out  (fp32 out)
// Same 2-phase double-buffer + launch_bounds(256,3) as qkv. XCD swizzle keeps
// same-bg chunks (and their 4 col-tiles) on one XCD -> w2t[bg] L2-resident.
// ---------------------------------------------------------------------------
__global__ __launch_bounds__(256, 3) void final_gemm_kernel(
        const __hip_bfloat16* __restrict__ qn, const __hip_bfloat16* __restrict__ w2t,
        const float* __restrict__ bias,
        const int* __restrict__ crow0, const int* __restrict__ crows,
        const int* __restrict__ cbg, const int* __restrict__ cnt,
        float* __restrict__ out) {
    __shared__ alignas(16) char smem[32768];   // A0|B0|A1|B1
    int bid = xcd_swizzle(blockIdx.y * 4 + blockIdx.x, 4 * MAXCHUNK);
    const int chunk = bid >> 2;
    if (chunk >= *cnt) return;
    const int row0  = crow0[chunk];
    const int nrows = crows[chunk];
    const int bg    = cbg[chunk];
    const int col0 = (bid & 3) * 128;
    const int t = threadIdx.x;
    const int lane = t & 63;
    const int wave = t >> 6;
    const int wr = wave >> 1, wc = wave & 1;
    const int quad = lane >> 4, lr = lane & 15;

    floatx4 acc[4][4] = {};

    const int srow = t >> 2;
    const int scol = (((t & 3) ^ ((t >> 3) & 3))) * 8;
    const __hip_bfloat16* gA = qn + (size_t)(row0 + srow) * INNER + scol;
    const __hip_bfloat16* gB = w2t + (size_t)bg * 512 * 512 + (size_t)(col0 + srow) * 512 + scol;
    char* lA = smem + t * 16;
    char* lB = smem + 8192 + t * 16;

    gl_lds16(gA, lA);
    gl_lds16(gA + (size_t)64 * INNER, lA + 4096);
    gl_lds16(gB, lB);
    gl_lds16(gB + (size_t)64 * 512, lB + 4096);
    __syncthreads();

    for (int it = 0; it < INNER / 32; ++it) {
        const int cb = (it & 1) << 14;
        const int nb = cb ^ 16384;
        const int k1 = (it + 1) * 32;
        if (k1 < INNER) {
            gl_lds16(gA + k1, lA + nb);
            gl_lds16(gA + (size_t)64 * INNER + k1, lA + nb + 4096);
            gl_lds16(gB + k1, lB + nb);
            gl_lds16(gB + (size_t)64 * 512 + k1, lB + nb + 4096);
        }
        bf16x8 af[4], bf[4];
        #pragma unroll
        for (int mt = 0; mt < 4; mt++)
            af[mt] = frag_ld(smem + cb, wr * 64 + mt * 16 + lr, quad);
        #pragma unroll
        for (int nt = 0; nt < 4; nt++)
            bf[nt] = frag_ld(smem + cb + 8192, wc * 64 + nt * 16 + lr, quad);
        #pragma unroll
        for (int mt = 0; mt < 4; mt++)
            #pragma unroll
            for (int nt = 0; nt < 4; nt++)
                acc[mt][nt] = __builtin_amdgcn_mfma_f32_16x16x32_bf16(af[mt], bf[nt], acc[mt][nt], 0, 0, 0);
        __syncthreads();
    }

    #pragma unroll
    for (int nt = 0; nt < 4; nt++) {
        int col = col0 + wc * 64 + nt * 16 + lr;
        float bv = bias[col];
        #pragma unroll
        for (int mt = 0; mt < 4; mt++)
            #pragma unroll
            for (int reg = 0; reg < 4; reg++) {
                int rl = wr * 64 + mt * 16 + quad * 4 + reg;
                if (rl < nrows)
                    out[(size_t)(row0 + rl) * DIM + col] = acc[mt][nt][reg] + bv;
            }
    }
}

// ---------------------------------------------------------------------------
extern "C" void kernel_launch(void* const* d_in, const int* in_sizes, int n_in,
                              void* d_out, int out_size, void* d_ws, size_t ws_size,
                              hipStream_t stream) {
    const float* x     = (const float*)d_in[0];
    const float* w_qkv = (const float*)d_in[1];
    const float* ln1w  = (const float*)d_in[2];
    const float* ln1b  = (const float*)d_in[3];
    const float* ln2w  = (const float*)d_in[4];
    const float* ln2b  = (const float*)d_in[5];
    const float* w_out = (const float*)d_in[6];
    const float* b_out = (const float*)d_in[7];
    const int*   batch = (const int*)d_in[8];
    float* out = (float*)d_out;

    char* ws = (char*)d_ws;
    const size_t MB = 1u << 20;
    __hip_bfloat16* qn  = (__hip_bfloat16*)(ws);              // 64 MiB
    __hip_bfloat16* kb  = (__hip_bfloat16*)(ws + 64 * MB);    // 64 MiB (transposed [bh][d][n])
    __hip_bfloat16* vb  = (__hip_bfloat16*)(ws + 128 * MB);   // 64 MiB (transposed [bh][d][n])
    __hip_bfloat16* xb  = (__hip_bfloat16*)(ws + 192 * MB);   // xb then w2t
    __hip_bfloat16* w2t = (__hip_bfloat16*)(ws + 192 * MB);
    __hip_bfloat16* wb  = (__hip_bfloat16*)(ws + 256 * MB);   // 1.5 MiB
    __hip_bfloat16* wob = (__hip_bfloat16*)(ws + 258 * MB);   // 0.5 MiB
    char* meta = ws + 259 * MB;
    int*   starts = (int*)(meta);
    int*   sizes  = (int*)(meta + 128);
    float* inv    = (float*)(meta + 256);
    int*   crow0  = (int*)(meta + 512);
    int*   crows  = (int*)(meta + 512 + 4096);
    int*   cbg    = (int*)(meta + 512 + 8192);
    int*   cnt    = (int*)(meta + 512 + 12288);

    graph_info_kernel<<<1, 64, 0, stream>>>(batch, starts, sizes, inv,
                                            crow0, crows, cbg, cnt);
    convert3_kernel<<<16896, 256, 0, stream>>>(x, w_qkv, w_out, xb, wb, wob);
    qkv_gemm_kernel<<<dim3((3 * INNER) / 128, M_ROWS / 128), 256, 0, stream>>>(
        xb, wb, ln1w, ln1b, ln2w, ln2b, inv, batch, qn, kb, vb);
    ktv_w2_kernel<<<BATCH * HEADS * G, 256, 0, stream>>>(
        (const short*)kb, (const short*)vb, (const short*)wob, starts, sizes, (short*)w2t);
    final_gemm_kernel<<<dim3(4, MAXCHUNK), 256, 0, stream>>>(
        qn, w2t, b_out, crow0, crows, cbg, cnt, out);
}